// Round 4
// baseline (829.424 us; speedup 1.0000x reference)
//
#include <hip/hip_runtime.h>
#include <hip/hip_bf16.h>

typedef __bf16 bf16;
typedef __bf16 bf16x8 __attribute__((ext_vector_type(8)));
typedef float floatx4 __attribute__((ext_vector_type(4)));

#define B_    8
#define N_    4096
#define C_    512
#define BN_   32768      // B_*N_
#define HID_  2048
#define SCALE_ 0.125f    // 64^-0.5

// ====================== dtype sniff: is input bf16-packed or fp32? =========
__global__ void sniff_kernel(const unsigned int* __restrict__ xw, int* __restrict__ flag)
{
    int t = threadIdx.x;
    int votes = 0;
#pragma unroll
    for (int i = 0; i < 4; i++) {
        unsigned w = xw[t * 4 + i];
        if (w == 0u) continue;
        unsigned a = w & 0xFFFFu;
        unsigned e = (a >> 7) & 0xFFu;
        if (a != 0u && e >= 110u && e <= 135u) votes++; else votes--;
    }
#pragma unroll
    for (int off = 32; off; off >>= 1) votes += __shfl_xor(votes, off);
    __shared__ int s[4];
    if ((t & 63) == 0) s[t >> 6] = votes;
    __syncthreads();
    if (t == 0) *flag = (s[0] + s[1] + s[2] + s[3]) > 0 ? 1 : 0;  // 1 = bf16
}

// ====================== param conversion (12 segments) =====================
struct ConvArgs {
    const void* src[12];
    unsigned    dstoff[12];   // byte offset into ws
    int         n[12];        // element count
};

__global__ __launch_bounds__(256) void convert_params(
    ConvArgs args, char* __restrict__ ws, const int* __restrict__ flag)
{
    int seg = blockIdx.y;
    int n = args.n[seg];
    int base = blockIdx.x * 2048;
    if (base >= n) return;
    bf16* dst = (bf16*)(ws + args.dstoff[seg]);
    const void* src = args.src[seg];
    bool isbf = (*flag != 0);
#pragma unroll
    for (int j = 0; j < 8; j++) {
        int idx = base + threadIdx.x + j * 256;
        if (idx < n) {
            float v = isbf ? (float)((const bf16*)src)[idx]
                           : ((const float*)src)[idx];
            dst[idx] = (bf16)v;
        }
    }
}

// ====================== LayerNorm (dtype-aware input) ======================
__global__ __launch_bounds__(256) void ln_dyn_kernel(
    const void* __restrict__ xv, const bf16* __restrict__ w,
    const bf16* __restrict__ b, bf16* __restrict__ out, const int* __restrict__ flag)
{
    int wave = threadIdx.x >> 6, lane = threadIdx.x & 63;
    size_t row = (size_t)blockIdx.x * 4 + wave;
    float f[8];
    if (*flag) {
        bf16x8 v = *(const bf16x8*)((const bf16*)xv + row * C_ + lane * 8);
#pragma unroll
        for (int j = 0; j < 8; j++) f[j] = (float)v[j];
    } else {
        const float4* p = (const float4*)((const float*)xv + row * C_ + lane * 8);
        float4 v0 = p[0], v1 = p[1];
        f[0]=v0.x; f[1]=v0.y; f[2]=v0.z; f[3]=v0.w;
        f[4]=v1.x; f[5]=v1.y; f[6]=v1.z; f[7]=v1.w;
    }
    float s = 0.f, sq = 0.f;
#pragma unroll
    for (int j = 0; j < 8; j++) { s += f[j]; sq += f[j]*f[j]; }
#pragma unroll
    for (int off = 32; off; off >>= 1) { s += __shfl_xor(s, off); sq += __shfl_xor(sq, off); }
    float mean = s * (1.f/512.f);
    float var  = sq * (1.f/512.f) - mean*mean;
    float inv  = rsqrtf(var + 1e-5f);
    bf16x8 wv = *(const bf16x8*)(w + lane*8);
    bf16x8 bv = *(const bf16x8*)(b + lane*8);
    bf16x8 o;
#pragma unroll
    for (int j = 0; j < 8; j++) o[j] = (bf16)((f[j]-mean)*inv*(float)wv[j] + (float)bv[j]);
    *(bf16x8*)(out + row * C_ + lane*8) = o;
}

// LN with fp32 input (for LN2 reading x2 from d_out)
__global__ __launch_bounds__(256) void ln_f32_kernel(
    const float* __restrict__ x, const bf16* __restrict__ w,
    const bf16* __restrict__ b, bf16* __restrict__ out)
{
    int wave = threadIdx.x >> 6, lane = threadIdx.x & 63;
    size_t row = (size_t)blockIdx.x * 4 + wave;
    const float4* p = (const float4*)(x + row * C_ + lane * 8);
    float4 v0 = p[0], v1 = p[1];
    float f[8] = { v0.x, v0.y, v0.z, v0.w, v1.x, v1.y, v1.z, v1.w };
    float s = 0.f, sq = 0.f;
#pragma unroll
    for (int j = 0; j < 8; j++) { s += f[j]; sq += f[j]*f[j]; }
#pragma unroll
    for (int off = 32; off; off >>= 1) { s += __shfl_xor(s, off); sq += __shfl_xor(sq, off); }
    float mean = s * (1.f/512.f);
    float var  = sq * (1.f/512.f) - mean*mean;
    float inv  = rsqrtf(var + 1e-5f);
    bf16x8 wv = *(const bf16x8*)(w + lane*8);
    bf16x8 bv = *(const bf16x8*)(b + lane*8);
    bf16x8 o;
#pragma unroll
    for (int j = 0; j < 8; j++) o[j] = (bf16)((f[j]-mean)*inv*(float)wv[j] + (float)bv[j]);
    *(bf16x8*)(out + row * C_ + lane*8) = o;
}

// ====================== MFMA GEMM ==========================================
// C(MxN) = A(MxK) @ W(NxK)^T with epilogue variants. dims %128==0, K%32==0.
enum { EPI_NONE = 0, EPI_BIAS = 1, EPI_BIAS_RESID = 2, EPI_BIAS_GELU = 3, EPI_QKV = 4 };
// OutT: element type of Cout (float for the fp32 x2 write to d_out).

template<typename OutT, int EPI>
__global__ __launch_bounds__(256, 2) void gemm_bt(
    const bf16* __restrict__ A, const bf16* __restrict__ W,
    const bf16* __restrict__ bias, const void* __restrict__ resid,
    const int* __restrict__ flag,
    OutT* __restrict__ Cout, bf16* __restrict__ Cout2, int M, int Nn, int K)
{
    __shared__ bf16 As[128][32];
    __shared__ bf16 Bs[128][32];
    const int t = threadIdx.x;
    const int wave = t >> 6, lane = t & 63;
    const int quad = lane >> 4, l16 = lane & 15;
    const int m0 = blockIdx.y * 128, n0 = blockIdx.x * 128;
    const int wm = (wave & 1) * 64, wn = (wave >> 1) * 64;
    floatx4 acc[4][4] = {};

    for (int k0 = 0; k0 < K; k0 += 32) {
#pragma unroll
        for (int i = 0; i < 2; i++) {
            int chunk = t * 2 + i;               // 0..511
            int row = chunk >> 2, kc = (chunk & 3) * 8;
            *(bf16x8*)&As[row][kc] = *(const bf16x8*)&A[(size_t)(m0 + row) * K + k0 + kc];
            *(bf16x8*)&Bs[row][kc] = *(const bf16x8*)&W[(size_t)(n0 + row) * K + k0 + kc];
        }
        __syncthreads();
        bf16x8 af[4], bfr[4];
#pragma unroll
        for (int mi = 0; mi < 4; mi++) af[mi]  = *(const bf16x8*)&As[wm + mi*16 + l16][quad*8];
#pragma unroll
        for (int ni = 0; ni < 4; ni++) bfr[ni] = *(const bf16x8*)&Bs[wn + ni*16 + l16][quad*8];
#pragma unroll
        for (int mi = 0; mi < 4; mi++)
#pragma unroll
            for (int ni = 0; ni < 4; ni++)
                acc[mi][ni] = __builtin_amdgcn_mfma_f32_16x16x32_bf16(af[mi], bfr[ni], acc[mi][ni], 0, 0, 0);
        __syncthreads();
    }

    size_t ldc = (size_t)Nn; int csub = 0; bool to2 = false;
    if (EPI == EPI_QKV) {
        if (n0 >= 512) { to2 = true; ldc = 1024; csub = 512; }
        else           { ldc = 512; }
    }
    bool isbf = false;
    if (EPI == EPI_BIAS_RESID) isbf = (*flag != 0);

#pragma unroll
    for (int mi = 0; mi < 4; mi++) {
#pragma unroll
        for (int ni = 0; ni < 4; ni++) {
            int col = n0 + wn + ni*16 + l16;
            float bv = (EPI == EPI_BIAS || EPI == EPI_BIAS_RESID || EPI == EPI_BIAS_GELU)
                       ? (float)bias[col] : 0.f;
#pragma unroll
            for (int r = 0; r < 4; r++) {
                int rowg = m0 + wm + mi*16 + quad*4 + r;
                size_t idx = (size_t)rowg * ldc + (col - csub);
                float v = acc[mi][ni][r] + bv;
                if (EPI == EPI_BIAS_RESID) {
                    float rres = isbf ? (float)((const bf16*)resid)[idx]
                                      : ((const float*)resid)[idx];
                    v += rres;
                }
                if (EPI == EPI_BIAS_GELU)  v = 0.5f * v * (1.f + erff(v * 0.70710678118654752f));
                if (EPI == EPI_QKV && to2) Cout2[idx] = (bf16)v;
                else                       Cout[idx]  = (OutT)v;
            }
        }
    }
}

// ====================== attention ==========================================
// kv layout: [32768 tokens][1024] = k(h*64+d) | v(512 + h*64+e)
__global__ __launch_bounds__(256) void attn_logits_kernel(
    const bf16* __restrict__ kv, float* __restrict__ partial)
{
    int s = blockIdx.x, bh = blockIdx.y;
    int b = bh >> 3, h = bh & 7;
    __shared__ bf16 k_lds[128][64];
    __shared__ bf16 v_lds[128][64];
    int t = threadIdx.x;
    int d0 = (t >> 4) * 4, e0 = (t & 15) * 4;
    float acc[4][4] = {};
    for (int c = 0; c < 4; c++) {
        int nbase = s * 512 + c * 128;
#pragma unroll
        for (int i = 0; i < 4; i++) {
            int chunk = t * 4 + i;              // 0..1023
            int r = chunk >> 3, cc = (chunk & 7) * 8;
            size_t roff = ((size_t)b * N_ + nbase + r) * 1024 + h * 64 + cc;
            *(bf16x8*)&k_lds[r][cc] = *(const bf16x8*)&kv[roff];
            *(bf16x8*)&v_lds[r][cc] = *(const bf16x8*)&kv[roff + 512];
        }
        __syncthreads();
        for (int n = 0; n < 128; n++) {
            float kvv[4], vv[4];
#pragma unroll
            for (int i = 0; i < 4; i++) kvv[i] = (float)k_lds[n][d0+i];
#pragma unroll
            for (int j = 0; j < 4; j++) vv[j] = (float)v_lds[n][e0+j];
#pragma unroll
            for (int i = 0; i < 4; i++)
#pragma unroll
                for (int j = 0; j < 4; j++) acc[i][j] += kvv[i] * vv[j];
        }
        __syncthreads();
    }
    float* p = partial + ((size_t)bh * 8 + s) * 4096;
#pragma unroll
    for (int i = 0; i < 4; i++)
#pragma unroll
        for (int j = 0; j < 4; j++) p[(d0+i)*64 + e0+j] = acc[i][j] * SCALE_;
}

__global__ __launch_bounds__(256) void attn_softmax_kernel(
    const float* __restrict__ partial, float* __restrict__ attn)
{
    int bh = blockIdx.x;
    int wave = threadIdx.x >> 6, lane = threadIdx.x & 63;
    for (int r = 0; r < 16; r++) {
        int d = wave * 16 + r;
        float v = 0.f;
#pragma unroll
        for (int s = 0; s < 8; s++) v += partial[((size_t)bh*8 + s)*4096 + d*64 + lane];
        float m = v;
#pragma unroll
        for (int off = 32; off; off >>= 1) m = fmaxf(m, __shfl_xor(m, off));
        float p = expf(v - m);
        float sum = p;
#pragma unroll
        for (int off = 32; off; off >>= 1) sum += __shfl_xor(sum, off);
        attn[(size_t)bh*4096 + d*64 + lane] = p / sum;
    }
}

// out[n, h*64+d] = sum_e attn[d,e] * q[n, h*64+e]; q is bf16 (stored in d_out)
__global__ __launch_bounds__(256) void attn_apply_kernel(
    const bf16* __restrict__ q, const float* __restrict__ attn,
    bf16* __restrict__ outbuf)
{
    int bh = blockIdx.y; int b = bh >> 3, h = bh & 7;
    int n = blockIdx.x * 256 + threadIdx.x;
    __shared__ float a_lds[4096];
#pragma unroll
    for (int i = 0; i < 16; i++)
        a_lds[threadIdx.x * 16 + i] = attn[(size_t)bh * 4096 + threadIdx.x * 16 + i];
    __syncthreads();
    float qf[64];
    const bf16* qp = &q[((size_t)b * N_ + n) * C_ + h * 64];
#pragma unroll
    for (int i = 0; i < 8; i++) {
        bf16x8 qv = *(const bf16x8*)(qp + i*8);
#pragma unroll
        for (int j = 0; j < 8; j++) qf[i*8+j] = (float)qv[j];
    }
    bf16* op = &outbuf[((size_t)b * N_ + n) * C_ + h * 64];
    for (int dg = 0; dg < 8; dg++) {
        bf16x8 o;
#pragma unroll
        for (int dd = 0; dd < 8; dd++) {
            int d = dg*8 + dd;
            float sum = 0.f;
#pragma unroll
            for (int e = 0; e < 64; e++) sum += a_lds[d*64 + e] * qf[e];
            o[dd] = (bf16)sum;
        }
        *(bf16x8*)(op + dg*8) = o;
    }
}

// ====================== ECA ================================================
__global__ __launch_bounds__(256) void pooled_kernel(
    const bf16* __restrict__ y, float* __restrict__ pooled)
{
    int bc = blockIdx.x;                       // b*512 + c
    const bf16* p = y + (size_t)bc * 4096 + threadIdx.x * 16;
    float s = 0.f;
#pragma unroll
    for (int i = 0; i < 2; i++) {
        bf16x8 v = *(const bf16x8*)(p + i*8);
#pragma unroll
        for (int j = 0; j < 8; j++) s += (float)v[j];
    }
#pragma unroll
    for (int off = 32; off; off >>= 1) s += __shfl_xor(s, off);
    __shared__ float red[4];
    if ((threadIdx.x & 63) == 0) red[threadIdx.x >> 6] = s;
    __syncthreads();
    if (threadIdx.x == 0)
        pooled[bc] = (red[0] + red[1] + red[2] + red[3]) * (1.f/4096.f);
}

__global__ void gate_kernel(const float* __restrict__ pooled,
                            const bf16* __restrict__ eca_w, float* __restrict__ gate1)
{
    int c = threadIdx.x, b = blockIdx.x;
    float w0 = (float)eca_w[0], w1 = (float)eca_w[1], w2 = (float)eca_w[2];
    const float* p = pooled + b * 512;
    float conv = w1 * p[c];
    if (c > 0)   conv += w0 * p[c-1];
    if (c < 511) conv += w2 * p[c+1];
    float g = 1.f / (1.f + expf(-conv));
    gate1[b * 512 + c] = 1.f + g;
}

// out[b,n,c] += gate1[b,c] * y_flat[b, c*4096 + n]   (in place, fp32 out)
__global__ __launch_bounds__(256) void final_kernel(
    const bf16* __restrict__ y, const float* __restrict__ gate1,
    float* __restrict__ out)
{
    int b = blockIdx.z, c0 = blockIdx.y * 64, n0 = blockIdx.x * 64;
    __shared__ float ytile[64][65];
    int t = threadIdx.x;
#pragma unroll
    for (int i = 0; i < 2; i++) {
        int chunk = t * 2 + i;                 // 0..511
        int ci = chunk >> 3, nj = (chunk & 7) * 8;
        bf16x8 v = *(const bf16x8*)&y[(size_t)b * ((size_t)N_*C_) + (size_t)(c0+ci) * 4096 + n0 + nj];
#pragma unroll
        for (int j = 0; j < 8; j++) ytile[ci][nj+j] = (float)v[j];
    }
    __syncthreads();
    int cc = t & 63, nb = t >> 6;
    float g = gate1[b * 512 + c0 + cc];
    for (int p = 0; p < 16; p++) {
        int nr = p * 4 + nb;
        size_t idx = ((size_t)b * N_ + n0 + nr) * C_ + c0 + cc;
        out[idx] = out[idx] + g * ytile[cc][nr];
    }
}

// ====================== launcher ===========================================
// ws layout (high-water 112 MB):
//   0: flag | 4K: pooled | 20K: gate1 | 64K-84K: small params bf16
//   1M: qkv_w | 2.5M: proj_w | 3M: fc1_w | 5M: fc2_w
//   7M-15M: partial | 15M-16M: attn
//   16M-80M: kv  -> reused: 16M-48M h-chunk, 48M-80M y
//   80M-112M: T1 (ln1out -> attnout -> ln2out)
// q (bf16) transiently in d_out; x2 (fp32) in d_out; final RMW fp32.
extern "C" void kernel_launch(void* const* d_in, const int* in_sizes, int n_in,
                              void* d_out, int out_size, void* d_ws, size_t ws_size,
                              hipStream_t stream)
{
    float* outf = (float*)d_out;
    bf16*  outb = (bf16*)d_out;
    char* ws = (char*)d_ws;

    int*   flag    = (int*)ws;
    float* pooled  = (float*)(ws + 4096);
    float* gate1   = (float*)(ws + 20480);
    bf16* ln1_w = (bf16*)(ws + 65536);
    bf16* ln1_b = (bf16*)(ws + 67584);
    bf16* ln2_w = (bf16*)(ws + 69632);
    bf16* ln2_b = (bf16*)(ws + 71680);
    bf16* proj_b= (bf16*)(ws + 73728);
    bf16* fc2_b = (bf16*)(ws + 75776);
    bf16* eca_w = (bf16*)(ws + 77824);
    bf16* fc1_b = (bf16*)(ws + 81920);
    bf16* qkv_w = (bf16*)(ws + ((size_t)1 << 20));
    bf16* proj_w= (bf16*)(ws + (size_t)(2621440));       // 2.5M
    bf16* fc1_w = (bf16*)(ws + ((size_t)3 << 20));
    bf16* fc2_w = (bf16*)(ws + ((size_t)5 << 20));
    float* partial = (float*)(ws + ((size_t)7  << 20));
    float* attn    = (float*)(ws + ((size_t)15 << 20));
    bf16*  kvbuf   = (bf16*)(ws + ((size_t)16 << 20));
    bf16*  hbuf    = (bf16*)(ws + ((size_t)16 << 20));  // after kv dead
    bf16*  ybuf    = (bf16*)(ws + ((size_t)48 << 20));
    bf16*  T1      = (bf16*)(ws + ((size_t)80 << 20));

    // 0. sniff input dtype
    sniff_kernel<<<1, 256, 0, stream>>>((const unsigned int*)d_in[0], flag);

    // 1. convert params to bf16
    ConvArgs ca;
    const int   srcidx[12] = { 1, 2, 6, 7, 5, 11, 12, 9, 3, 4, 8, 10 };
    const unsigned offs[12] = { 65536, 67584, 69632, 71680, 73728, 75776, 77824, 81920,
                                1u<<20, 2621440u, 3u<<20, 5u<<20 };
    for (int i = 0; i < 12; i++) {
        ca.src[i] = d_in[srcidx[i]];
        ca.dstoff[i] = offs[i];
        ca.n[i] = in_sizes[srcidx[i]];
    }
    convert_params<<<dim3(512, 12), 256, 0, stream>>>(ca, ws, flag);

    // 2. LN1 (dtype-aware x) -> T1
    ln_dyn_kernel<<<BN_/4, 256, 0, stream>>>(d_in[0], ln1_w, ln1_b, T1, flag);

    // 3. QKV GEMM: q (bf16) -> d_out, kv -> kvbuf
    gemm_bt<bf16, EPI_QKV><<<dim3(12, 256), 256, 0, stream>>>(
        T1, qkv_w, nullptr, nullptr, flag, outb, kvbuf, BN_, 1536, 512);

    // 4. attention
    attn_logits_kernel<<<dim3(8, 64), 256, 0, stream>>>(kvbuf, partial);
    attn_softmax_kernel<<<64, 256, 0, stream>>>(partial, attn);
    attn_apply_kernel<<<dim3(16, 64), 256, 0, stream>>>(outb, attn, T1);

    // 5. proj + bias + residual(raw x) -> x2 (fp32) in d_out
    gemm_bt<float, EPI_BIAS_RESID><<<dim3(4, 256), 256, 0, stream>>>(
        T1, proj_w, proj_b, d_in[0], flag, outf, nullptr, BN_, 512, 512);

    // 6. LN2: d_out (fp32) -> T1
    ln_f32_kernel<<<BN_/4, 256, 0, stream>>>(outf, ln2_w, ln2_b, T1);

    // 7-8. FC1(+gelu) / FC2(+bias), row-chunked x4
    for (int ch = 0; ch < 4; ch++) {
        const bf16* Ach = T1 + (size_t)ch * 8192 * 512;
        gemm_bt<bf16, EPI_BIAS_GELU><<<dim3(16, 64), 256, 0, stream>>>(
            Ach, fc1_w, fc1_b, nullptr, flag, hbuf, nullptr, 8192, 2048, 512);
        gemm_bt<bf16, EPI_BIAS><<<dim3(4, 64), 256, 0, stream>>>(
            hbuf, fc2_w, fc2_b, nullptr, flag, ybuf + (size_t)ch * 8192 * 512, nullptr,
            8192, 512, 2048);
    }

    // 9. ECA pooled + gate
    pooled_kernel<<<4096, 256, 0, stream>>>(ybuf, pooled);
    gate_kernel<<<8, 512, 0, stream>>>(pooled, eca_w, gate1);

    // 10. final gather + gated residual, in place on fp32 d_out
    final_kernel<<<dim3(64, 8, 8), 256, 0, stream>>>(ybuf, gate1, outf);
}

// Round 5
// 581.538 us; speedup vs baseline: 1.4263x; 1.4263x over previous
//
#include <hip/hip_runtime.h>
#include <hip/hip_bf16.h>

typedef __bf16 bf16;
typedef __bf16 bf16x8 __attribute__((ext_vector_type(8)));
typedef float floatx4 __attribute__((ext_vector_type(4)));

#define B_    8
#define N_    4096
#define C_    512
#define BN_   32768      // B_*N_
#define HID_  2048
#define SCALE_ 0.125f    // 64^-0.5

// async 16B global -> LDS (m97: the single biggest GEMM lever)
__device__ __forceinline__ void load_lds16(const void* g, void* l) {
    __builtin_amdgcn_global_load_lds(
        (const __attribute__((address_space(1))) void*)g,
        (__attribute__((address_space(3))) void*)l, 16, 0, 0);
}

// ====================== dtype sniff: is input bf16-packed or fp32? =========
__global__ void sniff_kernel(const unsigned int* __restrict__ xw, int* __restrict__ flag)
{
    int t = threadIdx.x;
    int votes = 0;
#pragma unroll
    for (int i = 0; i < 4; i++) {
        unsigned w = xw[t * 4 + i];
        if (w == 0u) continue;
        unsigned a = w & 0xFFFFu;
        unsigned e = (a >> 7) & 0xFFu;
        if (a != 0u && e >= 110u && e <= 135u) votes++; else votes--;
    }
#pragma unroll
    for (int off = 32; off; off >>= 1) votes += __shfl_xor(votes, off);
    __shared__ int s[4];
    if ((t & 63) == 0) s[t >> 6] = votes;
    __syncthreads();
    if (t == 0) *flag = (s[0] + s[1] + s[2] + s[3]) > 0 ? 1 : 0;  // 1 = bf16
}

// ====================== param conversion (12 segments) =====================
struct ConvArgs {
    const void* src[12];
    unsigned    dstoff[12];
    int         n[12];
};

__global__ __launch_bounds__(256) void convert_params(
    ConvArgs args, char* __restrict__ ws, const int* __restrict__ flag)
{
    int seg = blockIdx.y;
    int n = args.n[seg];
    int base = blockIdx.x * 2048;
    if (base >= n) return;
    bf16* dst = (bf16*)(ws + args.dstoff[seg]);
    const void* src = args.src[seg];
    bool isbf = (*flag != 0);
#pragma unroll
    for (int j = 0; j < 8; j++) {
        int idx = base + threadIdx.x + j * 256;
        if (idx < n) {
            float v = isbf ? (float)((const bf16*)src)[idx]
                           : ((const float*)src)[idx];
            dst[idx] = (bf16)v;
        }
    }
}

// ====================== LayerNorm (dtype-aware input) ======================
__global__ __launch_bounds__(256) void ln_dyn_kernel(
    const void* __restrict__ xv, const bf16* __restrict__ w,
    const bf16* __restrict__ b, bf16* __restrict__ out, const int* __restrict__ flag)
{
    int wave = threadIdx.x >> 6, lane = threadIdx.x & 63;
    size_t row = (size_t)blockIdx.x * 4 + wave;
    float f[8];
    if (*flag) {
        bf16x8 v = *(const bf16x8*)((const bf16*)xv + row * C_ + lane * 8);
#pragma unroll
        for (int j = 0; j < 8; j++) f[j] = (float)v[j];
    } else {
        const float4* p = (const float4*)((const float*)xv + row * C_ + lane * 8);
        float4 v0 = p[0], v1 = p[1];
        f[0]=v0.x; f[1]=v0.y; f[2]=v0.z; f[3]=v0.w;
        f[4]=v1.x; f[5]=v1.y; f[6]=v1.z; f[7]=v1.w;
    }
    float s = 0.f, sq = 0.f;
#pragma unroll
    for (int j = 0; j < 8; j++) { s += f[j]; sq += f[j]*f[j]; }
#pragma unroll
    for (int off = 32; off; off >>= 1) { s += __shfl_xor(s, off); sq += __shfl_xor(sq, off); }
    float mean = s * (1.f/512.f);
    float var  = sq * (1.f/512.f) - mean*mean;
    float inv  = rsqrtf(var + 1e-5f);
    bf16x8 wv = *(const bf16x8*)(w + lane*8);
    bf16x8 bv = *(const bf16x8*)(b + lane*8);
    bf16x8 o;
#pragma unroll
    for (int j = 0; j < 8; j++) o[j] = (bf16)((f[j]-mean)*inv*(float)wv[j] + (float)bv[j]);
    *(bf16x8*)(out + row * C_ + lane*8) = o;
}

// LN with fp32 input (LN2 reading x2 from d_out)
__global__ __launch_bounds__(256) void ln_f32_kernel(
    const float* __restrict__ x, const bf16* __restrict__ w,
    const bf16* __restrict__ b, bf16* __restrict__ out)
{
    int wave = threadIdx.x >> 6, lane = threadIdx.x & 63;
    size_t row = (size_t)blockIdx.x * 4 + wave;
    const float4* p = (const float4*)(x + row * C_ + lane * 8);
    float4 v0 = p[0], v1 = p[1];
    float f[8] = { v0.x, v0.y, v0.z, v0.w, v1.x, v1.y, v1.z, v1.w };
    float s = 0.f, sq = 0.f;
#pragma unroll
    for (int j = 0; j < 8; j++) { s += f[j]; sq += f[j]*f[j]; }
#pragma unroll
    for (int off = 32; off; off >>= 1) { s += __shfl_xor(s, off); sq += __shfl_xor(sq, off); }
    float mean = s * (1.f/512.f);
    float var  = sq * (1.f/512.f) - mean*mean;
    float inv  = rsqrtf(var + 1e-5f);
    bf16x8 wv = *(const bf16x8*)(w + lane*8);
    bf16x8 bv = *(const bf16x8*)(b + lane*8);
    bf16x8 o;
#pragma unroll
    for (int j = 0; j < 8; j++) o[j] = (bf16)((f[j]-mean)*inv*(float)wv[j] + (float)bv[j]);
    *(bf16x8*)(out + row * C_ + lane*8) = o;
}

// ====================== MFMA GEMM (m97-style async staging) ================
enum { EPI_NONE = 0, EPI_BIAS = 1, EPI_BIAS_RESID = 2, EPI_BIAS_GELU = 3, EPI_QKV = 4 };

template<typename OutT, int EPI>
__global__ __launch_bounds__(256, 2) void gemm_bt(
    const bf16* __restrict__ A, const bf16* __restrict__ W,
    const bf16* __restrict__ bias, const void* __restrict__ resid,
    const int* __restrict__ flag,
    OutT* __restrict__ Cout, bf16* __restrict__ Cout2, int M, int Nn, int K)
{
    __shared__ bf16 As[128][32];
    __shared__ bf16 Bs[128][32];
    const int t = threadIdx.x;
    const int wave = t >> 6, lane = t & 63;
    const int quad = lane >> 4, l16 = lane & 15;
    const int m0 = blockIdx.y * 128, n0 = blockIdx.x * 128;
    const int wm = (wave & 1) * 64, wn = (wave >> 1) * 64;
    floatx4 acc[4][4] = {};

    for (int k0 = 0; k0 < K; k0 += 32) {
        // async stage: 512 chunks of 16B per tile; lane order == LDS order
#pragma unroll
        for (int i = 0; i < 2; i++) {
            int chunk = i * 256 + t;
            int row = chunk >> 2, kc = (chunk & 3) * 8;
            load_lds16(&A[(size_t)(m0 + row) * K + k0 + kc], &As[row][kc]);
            load_lds16(&W[(size_t)(n0 + row) * K + k0 + kc], &Bs[row][kc]);
        }
        __syncthreads();
        bf16x8 af[4], bfr[4];
#pragma unroll
        for (int mi = 0; mi < 4; mi++) af[mi]  = *(const bf16x8*)&As[wm + mi*16 + l16][quad*8];
#pragma unroll
        for (int ni = 0; ni < 4; ni++) bfr[ni] = *(const bf16x8*)&Bs[wn + ni*16 + l16][quad*8];
#pragma unroll
        for (int mi = 0; mi < 4; mi++)
#pragma unroll
            for (int ni = 0; ni < 4; ni++)
                acc[mi][ni] = __builtin_amdgcn_mfma_f32_16x16x32_bf16(af[mi], bfr[ni], acc[mi][ni], 0, 0, 0);
        __syncthreads();
    }

    size_t ldc = (size_t)Nn; int csub = 0; bool to2 = false;
    if (EPI == EPI_QKV) {
        if (n0 >= 512) { to2 = true; ldc = 1024; csub = 512; }
        else           { ldc = 512; }
    }
    bool isbf = false;
    if (EPI == EPI_BIAS_RESID) isbf = (*flag != 0);

#pragma unroll
    for (int mi = 0; mi < 4; mi++) {
#pragma unroll
        for (int ni = 0; ni < 4; ni++) {
            int col = n0 + wn + ni*16 + l16;
            float bv = (EPI == EPI_BIAS || EPI == EPI_BIAS_RESID || EPI == EPI_BIAS_GELU)
                       ? (float)bias[col] : 0.f;
#pragma unroll
            for (int r = 0; r < 4; r++) {
                int rowg = m0 + wm + mi*16 + quad*4 + r;
                size_t idx = (size_t)rowg * ldc + (col - csub);
                float v = acc[mi][ni][r] + bv;
                if (EPI == EPI_BIAS_RESID) {
                    float rres = isbf ? (float)((const bf16*)resid)[idx]
                                      : ((const float*)resid)[idx];
                    v += rres;
                }
                if (EPI == EPI_BIAS_GELU)  v = 0.5f * v * (1.f + erff(v * 0.70710678118654752f));
                if (EPI == EPI_QKV && to2) Cout2[idx] = (bf16)v;
                else                       Cout[idx]  = (OutT)v;
            }
        }
    }
}

// ====================== attention (MFMA) ===================================
// logits: partial[(bh*4+s)*4096 + d*64+e] = sum over 1024 tokens of k[n][d]*v[n][e]
// grid (4, 64), block 256. K/V staged transposed in LDS (pad 136: 16B rows).
__global__ __launch_bounds__(256) void attn_logits_mfma(
    const bf16* __restrict__ kv, float* __restrict__ partial)
{
    __shared__ bf16 Kt[64][136];
    __shared__ bf16 Vt[64][136];
    int s = blockIdx.x, bh = blockIdx.y, b = bh >> 3, h = bh & 7;
    int t = threadIdx.x, wave = t >> 6, lane = t & 63;
    int quad = lane >> 4, l16 = lane & 15;
    floatx4 acc[4] = {};
    for (int c = 0; c < 8; c++) {
        int n0 = s * 1024 + c * 128;
        {
            int isv = t >> 7;            // threads 0-127: K rows; 128-255: V rows
            int r   = t & 127;
            const bf16* gp = &kv[((size_t)b * N_ + n0 + r) * 1024 + h * 64 + isv * 512];
            bf16x8 rowv[8];
#pragma unroll
            for (int u = 0; u < 8; u++) rowv[u] = *(const bf16x8*)(gp + u * 8);
            bf16 (*dst)[136] = isv ? Vt : Kt;
#pragma unroll
            for (int u = 0; u < 8; u++)
#pragma unroll
                for (int j = 0; j < 8; j++)
                    dst[u * 8 + j][r] = rowv[u][j];
        }
        __syncthreads();
#pragma unroll
        for (int ks = 0; ks < 4; ks++) {
            bf16x8 af = *(const bf16x8*)&Kt[wave * 16 + l16][ks * 32 + quad * 8];
#pragma unroll
            for (int ni = 0; ni < 4; ni++) {
                bf16x8 bfv = *(const bf16x8*)&Vt[ni * 16 + l16][ks * 32 + quad * 8];
                acc[ni] = __builtin_amdgcn_mfma_f32_16x16x32_bf16(af, bfv, acc[ni], 0, 0, 0);
            }
        }
        __syncthreads();
    }
    float* p = partial + ((size_t)bh * 4 + s) * 4096;
#pragma unroll
    for (int ni = 0; ni < 4; ni++)
#pragma unroll
        for (int r = 0; r < 4; r++)
            p[(wave * 16 + quad * 4 + r) * 64 + ni * 16 + l16] = acc[ni][r];
}

// softmax over e per (bh,d); reads 4 fp32 partials, writes bf16 attn weights
__global__ __launch_bounds__(256) void attn_softmax_kernel(
    const float* __restrict__ partial, bf16* __restrict__ attnb)
{
    int bh = blockIdx.x;
    int wave = threadIdx.x >> 6, lane = threadIdx.x & 63;
    for (int r = 0; r < 16; r++) {
        int d = wave * 16 + r;
        float v = 0.f;
#pragma unroll
        for (int s = 0; s < 4; s++) v += partial[((size_t)bh*4 + s)*4096 + d*64 + lane];
        v *= SCALE_;
        float m = v;
#pragma unroll
        for (int off = 32; off; off >>= 1) m = fmaxf(m, __shfl_xor(m, off));
        float p = expf(v - m);
        float sum = p;
#pragma unroll
        for (int off = 32; off; off >>= 1) sum += __shfl_xor(sum, off);
        attnb[(size_t)bh*4096 + d*64 + lane] = (bf16)(p / sum);
    }
}

// apply: outT[n][h*64+d] = sum_e attn[d][e] * q[n][h*64+e]
// grid (16, 64), block 256; fragments straight from global (64B-coalesced)
__global__ __launch_bounds__(256) void attn_apply_mfma(
    const bf16* __restrict__ q, const bf16* __restrict__ attnb,
    bf16* __restrict__ outT)
{
    int bh = blockIdx.y, b = bh >> 3, h = bh & 7;
    int t = threadIdx.x, wave = t >> 6, lane = t & 63;
    int quad = lane >> 4, l16 = lane & 15;
    int nbase = blockIdx.x * 256 + wave * 64;
    bf16x8 bfrag[4][2];
#pragma unroll
    for (int di = 0; di < 4; di++)
#pragma unroll
        for (int ks = 0; ks < 2; ks++)
            bfrag[di][ks] = *(const bf16x8*)&attnb[(size_t)bh*4096 + (di*16 + l16)*64 + ks*32 + quad*8];
    floatx4 acc[4][4] = {};
#pragma unroll
    for (int mi = 0; mi < 4; mi++) {
#pragma unroll
        for (int ks = 0; ks < 2; ks++) {
            bf16x8 af = *(const bf16x8*)&q[((size_t)b*N_ + nbase + mi*16 + l16)*512 + h*64 + ks*32 + quad*8];
#pragma unroll
            for (int di = 0; di < 4; di++)
                acc[mi][di] = __builtin_amdgcn_mfma_f32_16x16x32_bf16(af, bfrag[di][ks], acc[mi][di], 0, 0, 0);
        }
    }
#pragma unroll
    for (int mi = 0; mi < 4; mi++)
#pragma unroll
        for (int di = 0; di < 4; di++)
#pragma unroll
            for (int r = 0; r < 4; r++)
                outT[((size_t)b*N_ + nbase + mi*16 + quad*4 + r)*512 + h*64 + di*16 + l16] =
                    (bf16)acc[mi][di][r];
}

// ====================== ECA ================================================
__global__ __launch_bounds__(256) void pooled_kernel(
    const bf16* __restrict__ y, float* __restrict__ pooled)
{
    int bc = blockIdx.x;                       // b*512 + c
    const bf16* p = y + (size_t)bc * 4096 + threadIdx.x * 16;
    float s = 0.f;
#pragma unroll
    for (int i = 0; i < 2; i++) {
        bf16x8 v = *(const bf16x8*)(p + i*8);
#pragma unroll
        for (int j = 0; j < 8; j++) s += (float)v[j];
    }
#pragma unroll
    for (int off = 32; off; off >>= 1) s += __shfl_xor(s, off);
    __shared__ float red[4];
    if ((threadIdx.x & 63) == 0) red[threadIdx.x >> 6] = s;
    __syncthreads();
    if (threadIdx.x == 0)
        pooled[bc] = (red[0] + red[1] + red[2] + red[3]) * (1.f/4096.f);
}

__global__ void gate_kernel(const float* __restrict__ pooled,
                            const bf16* __restrict__ eca_w, float* __restrict__ gate1)
{
    int c = threadIdx.x, b = blockIdx.x;
    float w0 = (float)eca_w[0], w1 = (float)eca_w[1], w2 = (float)eca_w[2];
    const float* p = pooled + b * 512;
    float conv = w1 * p[c];
    if (c > 0)   conv += w0 * p[c-1];
    if (c < 511) conv += w2 * p[c+1];
    float g = 1.f / (1.f + expf(-conv));
    gate1[b * 512 + c] = 1.f + g;
}

// out[b,n,c] += gate1[b,c] * y_flat[b, c*4096 + n]   (in place, fp32 out)
__global__ __launch_bounds__(256) void final_kernel(
    const bf16* __restrict__ y, const float* __restrict__ gate1,
    float* __restrict__ out)
{
    int b = blockIdx.z, c0 = blockIdx.y * 64, n0 = blockIdx.x * 64;
    __shared__ float ytile[64][65];
    int t = threadIdx.x;
#pragma unroll
    for (int i = 0; i < 2; i++) {
        int chunk = t * 2 + i;                 // 0..511
        int ci = chunk >> 3, nj = (chunk & 7) * 8;
        bf16x8 v = *(const bf16x8*)&y[(size_t)b * ((size_t)N_*C_) + (size_t)(c0+ci) * 4096 + n0 + nj];
#pragma unroll
        for (int j = 0; j < 8; j++) ytile[ci][nj+j] = (float)v[j];
    }
    __syncthreads();
    int cc = t & 63, nb = t >> 6;
    float g = gate1[b * 512 + c0 + cc];
    for (int p = 0; p < 16; p++) {
        int nr = p * 4 + nb;
        size_t idx = ((size_t)b * N_ + n0 + nr) * C_ + c0 + cc;
        out[idx] = out[idx] + g * ytile[cc][nr];
    }
}

// ====================== launcher ===========================================
// ws layout (high-water 112 MB, same as passing r4):
//   0: flag | 4K: pooled | 20K: gate1 | 64K-84K: small params bf16
//   1M: qkv_w | 2.5M: proj_w | 3M: fc1_w | 5M: fc2_w
//   7M-11M: partial fp32 (4 slices) | 11M-11.5M: attnb bf16
//   16M-48M: T1 (ln1out -> attnout -> ln2out -> y in place)
//   48M-112M: kv (64MB) -> reused as hbuf (2 chunks of 16384 rows)
// q (bf16) transiently in d_out; x2 (fp32) in d_out; final RMW fp32.
extern "C" void kernel_launch(void* const* d_in, const int* in_sizes, int n_in,
                              void* d_out, int out_size, void* d_ws, size_t ws_size,
                              hipStream_t stream)
{
    float* outf = (float*)d_out;
    bf16*  outb = (bf16*)d_out;
    char* ws = (char*)d_ws;

    int*   flag    = (int*)ws;
    float* pooled  = (float*)(ws + 4096);
    float* gate1   = (float*)(ws + 20480);
    bf16* ln1_w = (bf16*)(ws + 65536);
    bf16* ln1_b = (bf16*)(ws + 67584);
    bf16* ln2_w = (bf16*)(ws + 69632);
    bf16* ln2_b = (bf16*)(ws + 71680);
    bf16* proj_b= (bf16*)(ws + 73728);
    bf16* fc2_b = (bf16*)(ws + 75776);
    bf16* eca_w = (bf16*)(ws + 77824);
    bf16* fc1_b = (bf16*)(ws + 81920);
    bf16* qkv_w = (bf16*)(ws + ((size_t)1 << 20));
    bf16* proj_w= (bf16*)(ws + (size_t)2621440);
    bf16* fc1_w = (bf16*)(ws + ((size_t)3 << 20));
    bf16* fc2_w = (bf16*)(ws + ((size_t)5 << 20));
    float* partial = (float*)(ws + ((size_t)7  << 20));
    bf16*  attnb   = (bf16*)(ws + ((size_t)11 << 20));
    bf16*  T1      = (bf16*)(ws + ((size_t)16 << 20));
    bf16*  kvbuf   = (bf16*)(ws + ((size_t)48 << 20));
    bf16*  hbuf    = kvbuf;  // kv dead before FC1

    // 0. sniff input dtype
    sniff_kernel<<<1, 256, 0, stream>>>((const unsigned int*)d_in[0], flag);

    // 1. convert params to bf16
    ConvArgs ca;
    const int   srcidx[12] = { 1, 2, 6, 7, 5, 11, 12, 9, 3, 4, 8, 10 };
    const unsigned offs[12] = { 65536, 67584, 69632, 71680, 73728, 75776, 77824, 81920,
                                1u<<20, 2621440u, 3u<<20, 5u<<20 };
    for (int i = 0; i < 12; i++) {
        ca.src[i] = d_in[srcidx[i]];
        ca.dstoff[i] = offs[i];
        ca.n[i] = in_sizes[srcidx[i]];
    }
    convert_params<<<dim3(512, 12), 256, 0, stream>>>(ca, ws, flag);

    // 2. LN1 (dtype-aware x) -> T1
    ln_dyn_kernel<<<BN_/4, 256, 0, stream>>>(d_in[0], ln1_w, ln1_b, T1, flag);

    // 3. QKV GEMM: q (bf16) -> d_out, kv -> kvbuf
    gemm_bt<bf16, EPI_QKV><<<dim3(12, 256), 256, 0, stream>>>(
        T1, qkv_w, nullptr, nullptr, flag, outb, kvbuf, BN_, 1536, 512);

    // 4. attention (MFMA)
    attn_logits_mfma<<<dim3(4, 64), 256, 0, stream>>>(kvbuf, partial);
    attn_softmax_kernel<<<64, 256, 0, stream>>>(partial, attnb);
    attn_apply_mfma<<<dim3(16, 64), 256, 0, stream>>>(outb, attnb, T1);

    // 5. proj + bias + residual(raw x) -> x2 (fp32) in d_out
    gemm_bt<float, EPI_BIAS_RESID><<<dim3(4, 256), 256, 0, stream>>>(
        T1, proj_w, proj_b, d_in[0], flag, outf, nullptr, BN_, 512, 512);

    // 6. LN2: d_out (fp32) -> T1
    ln_f32_kernel<<<BN_/4, 256, 0, stream>>>(outf, ln2_w, ln2_b, T1);

    // 7-8. FC1(+gelu) / FC2(+bias), 2 chunks of 16384 rows; y -> T1 in place
    for (int ch = 0; ch < 2; ch++) {
        bf16* Tch = T1 + (size_t)ch * 16384 * 512;
        gemm_bt<bf16, EPI_BIAS_GELU><<<dim3(16, 128), 256, 0, stream>>>(
            Tch, fc1_w, fc1_b, nullptr, flag, hbuf, nullptr, 16384, 2048, 512);
        gemm_bt<bf16, EPI_BIAS><<<dim3(4, 128), 256, 0, stream>>>(
            hbuf, fc2_w, fc2_b, nullptr, flag, Tch, nullptr, 16384, 512, 2048);
    }

    // 9. ECA pooled + gate (y lives in T1)
    pooled_kernel<<<4096, 256, 0, stream>>>(T1, pooled);
    gate_kernel<<<8, 512, 0, stream>>>(pooled, eca_w, gate1);

    // 10. final gather + gated residual, in place on fp32 d_out
    final_kernel<<<dim3(64, 8, 8), 256, 0, stream>>>(T1, gate1, outf);
}

// Round 6
// 542.694 us; speedup vs baseline: 1.5283x; 1.0716x over previous
//
#include <hip/hip_runtime.h>
#include <hip/hip_bf16.h>

typedef __bf16 bf16;
typedef __bf16 bf16x8 __attribute__((ext_vector_type(8)));
typedef float floatx4 __attribute__((ext_vector_type(4)));

#define B_    8
#define N_    4096
#define C_    512
#define BN_   32768      // B_*N_
#define HID_  2048
#define SCALE_ 0.125f    // 64^-0.5

// async 16B global -> LDS (m97 lever)
__device__ __forceinline__ void load_lds16(const void* g, void* l) {
    __builtin_amdgcn_global_load_lds(
        (const __attribute__((address_space(1))) void*)g,
        (__attribute__((address_space(3))) void*)l, 16, 0, 0);
}

// ====================== dtype sniff ========================================
__global__ void sniff_kernel(const unsigned int* __restrict__ xw, int* __restrict__ flag)
{
    int t = threadIdx.x;
    int votes = 0;
#pragma unroll
    for (int i = 0; i < 4; i++) {
        unsigned w = xw[t * 4 + i];
        if (w == 0u) continue;
        unsigned a = w & 0xFFFFu;
        unsigned e = (a >> 7) & 0xFFu;
        if (a != 0u && e >= 110u && e <= 135u) votes++; else votes--;
    }
#pragma unroll
    for (int off = 32; off; off >>= 1) votes += __shfl_xor(votes, off);
    __shared__ int s[4];
    if ((t & 63) == 0) s[t >> 6] = votes;
    __syncthreads();
    if (t == 0) *flag = (s[0] + s[1] + s[2] + s[3]) > 0 ? 1 : 0;  // 1 = bf16
}

// ====================== param conversion ===================================
struct ConvArgs {
    const void* src[12];
    unsigned    dstoff[12];
    int         n[12];
};

__global__ __launch_bounds__(256) void convert_params(
    ConvArgs args, char* __restrict__ ws, const int* __restrict__ flag)
{
    int seg = blockIdx.y;
    int n = args.n[seg];
    int base = blockIdx.x * 2048;
    if (base >= n) return;
    bf16* dst = (bf16*)(ws + args.dstoff[seg]);
    const void* src = args.src[seg];
    bool isbf = (*flag != 0);
#pragma unroll
    for (int j = 0; j < 8; j++) {
        int idx = base + threadIdx.x + j * 256;
        if (idx < n) {
            float v = isbf ? (float)((const bf16*)src)[idx]
                           : ((const float*)src)[idx];
            dst[idx] = (bf16)v;
        }
    }
}

// ====================== LayerNorm variants =================================
__device__ __forceinline__ void ln_core(float f[8], const bf16* w, const bf16* b,
                                        int lane, bf16* outp)
{
    float s = 0.f, sq = 0.f;
#pragma unroll
    for (int j = 0; j < 8; j++) { s += f[j]; sq += f[j]*f[j]; }
#pragma unroll
    for (int off = 32; off; off >>= 1) { s += __shfl_xor(s, off); sq += __shfl_xor(sq, off); }
    float mean = s * (1.f/512.f);
    float var  = sq * (1.f/512.f) - mean*mean;
    float inv  = rsqrtf(var + 1e-5f);
    bf16x8 wv = *(const bf16x8*)(w + lane*8);
    bf16x8 bv = *(const bf16x8*)(b + lane*8);
    bf16x8 o;
#pragma unroll
    for (int j = 0; j < 8; j++) o[j] = (bf16)((f[j]-mean)*inv*(float)wv[j] + (float)bv[j]);
    *(bf16x8*)outp = o;
}

__global__ __launch_bounds__(256) void ln_dyn_kernel(
    const void* __restrict__ xv, const bf16* __restrict__ w,
    const bf16* __restrict__ b, bf16* __restrict__ out, const int* __restrict__ flag)
{
    int wave = threadIdx.x >> 6, lane = threadIdx.x & 63;
    size_t row = (size_t)blockIdx.x * 4 + wave;
    float f[8];
    if (*flag) {
        bf16x8 v = *(const bf16x8*)((const bf16*)xv + row * C_ + lane * 8);
#pragma unroll
        for (int j = 0; j < 8; j++) f[j] = (float)v[j];
    } else {
        const float4* p = (const float4*)((const float*)xv + row * C_ + lane * 8);
        float4 v0 = p[0], v1 = p[1];
        f[0]=v0.x; f[1]=v0.y; f[2]=v0.z; f[3]=v0.w;
        f[4]=v1.x; f[5]=v1.y; f[6]=v1.z; f[7]=v1.w;
    }
    ln_core(f, w, b, lane, out + row * C_ + lane*8);
}

__global__ __launch_bounds__(256) void ln_b16_kernel(
    const bf16* __restrict__ x, const bf16* __restrict__ w,
    const bf16* __restrict__ b, bf16* __restrict__ out)
{
    int wave = threadIdx.x >> 6, lane = threadIdx.x & 63;
    size_t row = (size_t)blockIdx.x * 4 + wave;
    bf16x8 v = *(const bf16x8*)(x + row * C_ + lane * 8);
    float f[8];
#pragma unroll
    for (int j = 0; j < 8; j++) f[j] = (float)v[j];
    ln_core(f, w, b, lane, out + row * C_ + lane*8);
}

__global__ __launch_bounds__(256) void ln_f32_kernel(
    const float* __restrict__ x, const bf16* __restrict__ w,
    const bf16* __restrict__ b, bf16* __restrict__ out)
{
    int wave = threadIdx.x >> 6, lane = threadIdx.x & 63;
    size_t row = (size_t)blockIdx.x * 4 + wave;
    const float4* p = (const float4*)(x + row * C_ + lane * 8);
    float4 v0 = p[0], v1 = p[1];
    float f[8] = { v0.x, v0.y, v0.z, v0.w, v1.x, v1.y, v1.z, v1.w };
    ln_core(f, w, b, lane, out + row * C_ + lane*8);
}

// ====================== MFMA GEMM (async staging + XCD-grouped 1D grid) ====
// 1D grid of Mt*Nt blocks; id&7 fixes the XCD class; all Nt n-tiles of one
// m-tile share the class -> A-tile fetched once per XCD L2 (not 8x).
enum { EPI_NONE = 0, EPI_BIAS = 1, EPI_BIAS_RESID = 2, EPI_BIAS_GELU = 3, EPI_QKV = 4 };

template<typename OutT, int EPI>
__global__ __launch_bounds__(256, 2) void gemm_bt(
    const bf16* __restrict__ A, const bf16* __restrict__ W,
    const bf16* __restrict__ bias, const void* __restrict__ resid,
    const int* __restrict__ flag,
    OutT* __restrict__ Cout, bf16* __restrict__ Cout2, int M, int Nn, int K)
{
    __shared__ bf16 As[128][32];
    __shared__ bf16 Bs[128][32];
    const int t = threadIdx.x;
    const int wave = t >> 6, lane = t & 63;
    const int quad = lane >> 4, l16 = lane & 15;
    // swizzle: id = 8*(mh*Nt + ntile) + xcd; m_idx = mh*8 + xcd
    const int Nt = Nn >> 7;
    const int id = blockIdx.x;
    const int xcd = id & 7, j = id >> 3;
    const int m0 = ((j / Nt) * 8 + xcd) * 128;
    const int n0 = (j % Nt) * 128;
    const int wm = (wave & 1) * 64, wn = (wave >> 1) * 64;
    floatx4 acc[4][4] = {};

    for (int k0 = 0; k0 < K; k0 += 32) {
#pragma unroll
        for (int i = 0; i < 2; i++) {
            int chunk = i * 256 + t;
            int row = chunk >> 2, kc = (chunk & 3) * 8;
            load_lds16(&A[(size_t)(m0 + row) * K + k0 + kc], &As[row][kc]);
            load_lds16(&W[(size_t)(n0 + row) * K + k0 + kc], &Bs[row][kc]);
        }
        __syncthreads();
        bf16x8 af[4], bfr[4];
#pragma unroll
        for (int mi = 0; mi < 4; mi++) af[mi]  = *(const bf16x8*)&As[wm + mi*16 + l16][quad*8];
#pragma unroll
        for (int ni = 0; ni < 4; ni++) bfr[ni] = *(const bf16x8*)&Bs[wn + ni*16 + l16][quad*8];
#pragma unroll
        for (int mi = 0; mi < 4; mi++)
#pragma unroll
            for (int ni = 0; ni < 4; ni++)
                acc[mi][ni] = __builtin_amdgcn_mfma_f32_16x16x32_bf16(af[mi], bfr[ni], acc[mi][ni], 0, 0, 0);
        __syncthreads();
    }

    size_t ldc = (size_t)Nn; int csub = 0; bool to2 = false;
    if (EPI == EPI_QKV) {
        if (n0 >= 512) { to2 = true; ldc = 1024; csub = 512; }
        else           { ldc = 512; }
    }
    bool isbf = false;
    if (EPI == EPI_BIAS_RESID) isbf = (*flag != 0);

#pragma unroll
    for (int mi = 0; mi < 4; mi++) {
#pragma unroll
        for (int ni = 0; ni < 4; ni++) {
            int col = n0 + wn + ni*16 + l16;
            float bv = (EPI == EPI_BIAS || EPI == EPI_BIAS_RESID || EPI == EPI_BIAS_GELU)
                       ? (float)bias[col] : 0.f;
#pragma unroll
            for (int r = 0; r < 4; r++) {
                int rowg = m0 + wm + mi*16 + quad*4 + r;
                size_t idx = (size_t)rowg * ldc + (col - csub);
                float v = acc[mi][ni][r] + bv;
                if (EPI == EPI_BIAS_RESID) {
                    float rres = isbf ? (float)((const bf16*)resid)[idx]
                                      : ((const float*)resid)[idx];
                    v += rres;
                }
                if (EPI == EPI_BIAS_GELU)  v = 0.5f * v * (1.f + erff(v * 0.70710678118654752f));
                if (EPI == EPI_QKV && to2) Cout2[idx] = (bf16)v;
                else                       Cout[idx]  = (OutT)v;
            }
        }
    }
}

// ====================== attention (MFMA) ===================================
// grid (8 slices, 64 bh): partial[(bh*8+s)*4096 + d*64+e] over 512 tokens
__global__ __launch_bounds__(256) void attn_logits_mfma(
    const bf16* __restrict__ kv, float* __restrict__ partial)
{
    __shared__ bf16 Kt[64][136];
    __shared__ bf16 Vt[64][136];
    int s = blockIdx.x, bh = blockIdx.y, b = bh >> 3, h = bh & 7;
    int t = threadIdx.x, wave = t >> 6, lane = t & 63;
    int quad = lane >> 4, l16 = lane & 15;
    floatx4 acc[4] = {};
    for (int c = 0; c < 4; c++) {
        int n0 = s * 512 + c * 128;
        {
            int isv = t >> 7;
            int r   = t & 127;
            const bf16* gp = &kv[((size_t)b * N_ + n0 + r) * 1024 + h * 64 + isv * 512];
            bf16x8 rowv[8];
#pragma unroll
            for (int u = 0; u < 8; u++) rowv[u] = *(const bf16x8*)(gp + u * 8);
            bf16 (*dst)[136] = isv ? Vt : Kt;
#pragma unroll
            for (int u = 0; u < 8; u++)
#pragma unroll
                for (int jj = 0; jj < 8; jj++)
                    dst[u * 8 + jj][r] = rowv[u][jj];
        }
        __syncthreads();
#pragma unroll
        for (int ks = 0; ks < 4; ks++) {
            bf16x8 af = *(const bf16x8*)&Kt[wave * 16 + l16][ks * 32 + quad * 8];
#pragma unroll
            for (int ni = 0; ni < 4; ni++) {
                bf16x8 bfv = *(const bf16x8*)&Vt[ni * 16 + l16][ks * 32 + quad * 8];
                acc[ni] = __builtin_amdgcn_mfma_f32_16x16x32_bf16(af, bfv, acc[ni], 0, 0, 0);
            }
        }
        __syncthreads();
    }
    float* p = partial + ((size_t)bh * 8 + s) * 4096;
#pragma unroll
    for (int ni = 0; ni < 4; ni++)
#pragma unroll
        for (int r = 0; r < 4; r++)
            p[(wave * 16 + quad * 4 + r) * 64 + ni * 16 + l16] = acc[ni][r];
}

// softmax: grid (4, 64); block handles 16 d rows (wave*4 + r)
__global__ __launch_bounds__(256) void attn_softmax_kernel(
    const float* __restrict__ partial, bf16* __restrict__ attnb)
{
    int bh = blockIdx.y;
    int wave = threadIdx.x >> 6, lane = threadIdx.x & 63;
    for (int r = 0; r < 4; r++) {
        int d = blockIdx.x * 16 + wave * 4 + r;
        float v = 0.f;
#pragma unroll
        for (int s = 0; s < 8; s++) v += partial[((size_t)bh*8 + s)*4096 + d*64 + lane];
        v *= SCALE_;
        float m = v;
#pragma unroll
        for (int off = 32; off; off >>= 1) m = fmaxf(m, __shfl_xor(m, off));
        float p = expf(v - m);
        float sum = p;
#pragma unroll
        for (int off = 32; off; off >>= 1) sum += __shfl_xor(sum, off);
        attnb[(size_t)bh*4096 + d*64 + lane] = (bf16)(p / sum);
    }
}

// apply: outT[n][h*64+d] = sum_e attn[d][e] * q[n][h*64+e]
__global__ __launch_bounds__(256) void attn_apply_mfma(
    const bf16* __restrict__ q, const bf16* __restrict__ attnb,
    bf16* __restrict__ outT)
{
    int bh = blockIdx.y, b = bh >> 3, h = bh & 7;
    int t = threadIdx.x, wave = t >> 6, lane = t & 63;
    int quad = lane >> 4, l16 = lane & 15;
    int nbase = blockIdx.x * 256 + wave * 64;
    bf16x8 bfrag[4][2];
#pragma unroll
    for (int di = 0; di < 4; di++)
#pragma unroll
        for (int ks = 0; ks < 2; ks++)
            bfrag[di][ks] = *(const bf16x8*)&attnb[(size_t)bh*4096 + (di*16 + l16)*64 + ks*32 + quad*8];
    floatx4 acc[4][4] = {};
#pragma unroll
    for (int mi = 0; mi < 4; mi++) {
#pragma unroll
        for (int ks = 0; ks < 2; ks++) {
            bf16x8 af = *(const bf16x8*)&q[((size_t)b*N_ + nbase + mi*16 + l16)*512 + h*64 + ks*32 + quad*8];
#pragma unroll
            for (int di = 0; di < 4; di++)
                acc[mi][di] = __builtin_amdgcn_mfma_f32_16x16x32_bf16(af, bfrag[di][ks], acc[mi][di], 0, 0, 0);
        }
    }
#pragma unroll
    for (int mi = 0; mi < 4; mi++)
#pragma unroll
        for (int di = 0; di < 4; di++)
#pragma unroll
            for (int r = 0; r < 4; r++)
                outT[((size_t)b*N_ + nbase + mi*16 + quad*4 + r)*512 + h*64 + di*16 + l16] =
                    (bf16)acc[mi][di][r];
}

// ====================== ECA ================================================
__global__ __launch_bounds__(256) void pooled_kernel(
    const bf16* __restrict__ y, float* __restrict__ pooled)
{
    int bc = blockIdx.x;
    const bf16* p = y + (size_t)bc * 4096 + threadIdx.x * 16;
    float s = 0.f;
#pragma unroll
    for (int i = 0; i < 2; i++) {
        bf16x8 v = *(const bf16x8*)(p + i*8);
#pragma unroll
        for (int j = 0; j < 8; j++) s += (float)v[j];
    }
#pragma unroll
    for (int off = 32; off; off >>= 1) s += __shfl_xor(s, off);
    __shared__ float red[4];
    if ((threadIdx.x & 63) == 0) red[threadIdx.x >> 6] = s;
    __syncthreads();
    if (threadIdx.x == 0)
        pooled[bc] = (red[0] + red[1] + red[2] + red[3]) * (1.f/4096.f);
}

__global__ void gate_kernel(const float* __restrict__ pooled,
                            const bf16* __restrict__ eca_w, float* __restrict__ gate1)
{
    int c = threadIdx.x, b = blockIdx.x;
    float w0 = (float)eca_w[0], w1 = (float)eca_w[1], w2 = (float)eca_w[2];
    const float* p = pooled + b * 512;
    float conv = w1 * p[c];
    if (c > 0)   conv += w0 * p[c-1];
    if (c < 511) conv += w2 * p[c+1];
    float g = 1.f / (1.f + expf(-conv));
    gate1[b * 512 + c] = 1.f + g;
}

// ------- final, layout B: RMW fp32 d_out -------
__global__ __launch_bounds__(256) void final_rmw(
    const bf16* __restrict__ y, const float* __restrict__ gate1,
    float* __restrict__ out)
{
    int b = blockIdx.z, c0 = blockIdx.y * 64, n0 = blockIdx.x * 64;
    __shared__ float ytile[64][65];
    int t = threadIdx.x;
#pragma unroll
    for (int i = 0; i < 2; i++) {
        int chunk = t * 2 + i;
        int ci = chunk >> 3, nj = (chunk & 7) * 8;
        bf16x8 v = *(const bf16x8*)&y[(size_t)b * ((size_t)N_*C_) + (size_t)(c0+ci) * 4096 + n0 + nj];
#pragma unroll
        for (int j = 0; j < 8; j++) ytile[ci][nj+j] = (float)v[j];
    }
    __syncthreads();
    int cc = t & 63, nb = t >> 6;
    float g = gate1[b * 512 + c0 + cc];
    for (int p = 0; p < 16; p++) {
        int nr = p * 4 + nb;
        size_t idx = ((size_t)b * N_ + n0 + nr) * C_ + c0 + cc;
        out[idx] = out[idx] + g * ytile[cc][nr];
    }
}

// ------- final, layout A: read bf16 x2, write fresh fp32 -------
__global__ __launch_bounds__(256) void final_fresh(
    const bf16* __restrict__ y, const bf16* __restrict__ x2b,
    const float* __restrict__ gate1, float* __restrict__ out)
{
    int b = blockIdx.z, c0 = blockIdx.y * 64, n0 = blockIdx.x * 64;
    __shared__ float ytile[64][65];
    int t = threadIdx.x;
#pragma unroll
    for (int i = 0; i < 2; i++) {
        int chunk = t * 2 + i;
        int ci = chunk >> 3, nj = (chunk & 7) * 8;
        bf16x8 v = *(const bf16x8*)&y[(size_t)b * ((size_t)N_*C_) + (size_t)(c0+ci) * 4096 + n0 + nj];
#pragma unroll
        for (int j = 0; j < 8; j++) ytile[ci][nj+j] = (float)v[j];
    }
    __syncthreads();
    int cc = t & 63, nb = t >> 6;
    float g = gate1[b * 512 + c0 + cc];
    for (int p = 0; p < 16; p++) {
        int nr = p * 4 + nb;
        size_t idx = ((size_t)b * N_ + n0 + nr) * C_ + c0 + cc;
        out[idx] = (float)x2b[idx] + g * ytile[cc][nr];
    }
}

// ====================== launcher ===========================================
// Common (both layouts):
//   0: flag | 4K: pooled | 20K: gate1 | 64K-84K: small params bf16
//   1M: qkv_w | 2.5M: proj_w | 3M: fc1_w | 5M: fc2_w
//   7M-15M: partial fp32 (8 slices) | 15M-15.5M: attnb bf16
//   16M-48M: T1 | 48M: kvbuf (64MB)
// Layout A (ws >= 212MB): hbuf 48-176M (full h), x2b bf16 176-210M,
//   proj->x2b, ln_b16, unchunked FC, final_fresh.
// Layout B: hbuf=kvbuf 48-112M, x2 fp32 in d_out, chunked FC, final_rmw.
extern "C" void kernel_launch(void* const* d_in, const int* in_sizes, int n_in,
                              void* d_out, int out_size, void* d_ws, size_t ws_size,
                              hipStream_t stream)
{
    float* outf = (float*)d_out;
    bf16*  outb = (bf16*)d_out;
    char* ws = (char*)d_ws;

    int*   flag    = (int*)ws;
    float* pooled  = (float*)(ws + 4096);
    float* gate1   = (float*)(ws + 20480);
    bf16* ln1_w = (bf16*)(ws + 65536);
    bf16* ln1_b = (bf16*)(ws + 67584);
    bf16* ln2_w = (bf16*)(ws + 69632);
    bf16* ln2_b = (bf16*)(ws + 71680);
    bf16* proj_b= (bf16*)(ws + 73728);
    bf16* fc2_b = (bf16*)(ws + 75776);
    bf16* eca_w = (bf16*)(ws + 77824);
    bf16* fc1_b = (bf16*)(ws + 81920);
    bf16* qkv_w = (bf16*)(ws + ((size_t)1 << 20));
    bf16* proj_w= (bf16*)(ws + (size_t)2621440);
    bf16* fc1_w = (bf16*)(ws + ((size_t)3 << 20));
    bf16* fc2_w = (bf16*)(ws + ((size_t)5 << 20));
    float* partial = (float*)(ws + ((size_t)7  << 20));
    bf16*  attnb   = (bf16*)(ws + ((size_t)15 << 20));
    bf16*  T1      = (bf16*)(ws + ((size_t)16 << 20));
    bf16*  kvbuf   = (bf16*)(ws + ((size_t)48 << 20));
    bf16*  hbuf    = kvbuf;
    bf16*  x2b     = (bf16*)(ws + ((size_t)176 << 20));

    const bool fat = ws_size >= ((size_t)212 << 20);

    // 0. sniff input dtype
    sniff_kernel<<<1, 256, 0, stream>>>((const unsigned int*)d_in[0], flag);

    // 1. convert params to bf16
    ConvArgs ca;
    const int   srcidx[12] = { 1, 2, 6, 7, 5, 11, 12, 9, 3, 4, 8, 10 };
    const unsigned offs[12] = { 65536, 67584, 69632, 71680, 73728, 75776, 77824, 81920,
                                1u<<20, 2621440u, 3u<<20, 5u<<20 };
    for (int i = 0; i < 12; i++) {
        ca.src[i] = d_in[srcidx[i]];
        ca.dstoff[i] = offs[i];
        ca.n[i] = in_sizes[srcidx[i]];
    }
    convert_params<<<dim3(512, 12), 256, 0, stream>>>(ca, ws, flag);

    // 2. LN1 -> T1
    ln_dyn_kernel<<<BN_/4, 256, 0, stream>>>(d_in[0], ln1_w, ln1_b, T1, flag);

    // 3. QKV GEMM: q (bf16) -> d_out, kv -> kvbuf   (Mt=256, Nt=12)
    gemm_bt<bf16, EPI_QKV><<<3072, 256, 0, stream>>>(
        T1, qkv_w, nullptr, nullptr, flag, outb, kvbuf, BN_, 1536, 512);

    // 4. attention
    attn_logits_mfma<<<dim3(8, 64), 256, 0, stream>>>(kvbuf, partial);
    attn_softmax_kernel<<<dim3(4, 64), 256, 0, stream>>>(partial, attnb);
    attn_apply_mfma<<<dim3(16, 64), 256, 0, stream>>>(outb, attnb, T1);

    if (fat) {
        // 5. proj + bias + residual(x) -> x2b (bf16)
        gemm_bt<bf16, EPI_BIAS_RESID><<<1024, 256, 0, stream>>>(
            T1, proj_w, proj_b, d_in[0], flag, x2b, nullptr, BN_, 512, 512);
        // 6. LN2: x2b -> T1
        ln_b16_kernel<<<BN_/4, 256, 0, stream>>>(x2b, ln2_w, ln2_b, T1);
        // 7. FC1 full: T1 -> hbuf (128MB)   (Mt=256, Nt=16)
        gemm_bt<bf16, EPI_BIAS_GELU><<<4096, 256, 0, stream>>>(
            T1, fc1_w, fc1_b, nullptr, flag, hbuf, nullptr, BN_, 2048, 512);
        // 8. FC2 full: hbuf -> T1 (y)       (Mt=256, Nt=4)
        gemm_bt<bf16, EPI_BIAS><<<1024, 256, 0, stream>>>(
            hbuf, fc2_w, fc2_b, nullptr, flag, T1, nullptr, BN_, 512, 2048);
        // 9. ECA
        pooled_kernel<<<4096, 256, 0, stream>>>(T1, pooled);
        gate_kernel<<<8, 512, 0, stream>>>(pooled, eca_w, gate1);
        // 10. final: fp32 out = x2b + gate*y  (no RMW)
        final_fresh<<<dim3(64, 8, 8), 256, 0, stream>>>(T1, x2b, gate1, outf);
    } else {
        // 5. proj + bias + residual(x) -> x2 (fp32) in d_out
        gemm_bt<float, EPI_BIAS_RESID><<<1024, 256, 0, stream>>>(
            T1, proj_w, proj_b, d_in[0], flag, outf, nullptr, BN_, 512, 512);
        // 6. LN2: d_out fp32 -> T1
        ln_f32_kernel<<<BN_/4, 256, 0, stream>>>(outf, ln2_w, ln2_b, T1);
        // 7-8. chunked FC (hbuf 64MB)
        for (int ch = 0; ch < 2; ch++) {
            bf16* Tch = T1 + (size_t)ch * 16384 * 512;
            gemm_bt<bf16, EPI_BIAS_GELU><<<2048, 256, 0, stream>>>(
                Tch, fc1_w, fc1_b, nullptr, flag, hbuf, nullptr, 16384, 2048, 512);
            gemm_bt<bf16, EPI_BIAS><<<512, 256, 0, stream>>>(
                hbuf, fc2_w, fc2_b, nullptr, flag, Tch, nullptr, 16384, 512, 2048);
        }
        // 9. ECA
        pooled_kernel<<<4096, 256, 0, stream>>>(T1, pooled);
        gate_kernel<<<8, 512, 0, stream>>>(pooled, eca_w, gate1);
        // 10. final RMW on fp32 d_out
        final_rmw<<<dim3(64, 8, 8), 256, 0, stream>>>(T1, gate1, outf);
    }
}